// Round 5
// baseline (379.589 us; speedup 1.0000x reference)
//
#include <hip/hip_runtime.h>
#include <cstdint>
#include <cstddef>

#define TPB 256

__device__ __forceinline__ ushort f2b(float f) {
    union { float f; uint32_t u; } v; v.f = f;
    uint32_t r = (v.u + 0x7FFFu + ((v.u >> 16) & 1u)) >> 16;
    return (ushort)r;
}
__device__ __forceinline__ float b2f(ushort h) {
    union { uint32_t u; float f; } v; v.u = ((uint32_t)h) << 16;
    return v.f;
}
__device__ __forceinline__ float b2f_lo(uint32_t u) {
    union { uint32_t u; float f; } v; v.u = u << 16;
    return v.f;
}
__device__ __forceinline__ float b2f_hi(uint32_t u) {
    union { uint32_t u; float f; } v; v.u = u & 0xFFFF0000u;
    return v.f;
}

// ---------------- CSR build (single-atomic: rank folded into count) ----------------

__global__ __launch_bounds__(TPB) void k_countrank(const int* __restrict__ dst, int* __restrict__ counts,
                                                   int* __restrict__ rank, int E) {
    int i = blockIdx.x * blockDim.x + threadIdx.x;
    if (i < E) rank[i] = atomicAdd(&counts[dst[i]], 1);
}

__global__ __launch_bounds__(TPB) void k_scan1(const int* __restrict__ counts, int* __restrict__ bsum, int total) {
    __shared__ int sh[TPB];
    int base = blockIdx.x * 1024;
    int s = 0;
#pragma unroll
    for (int j = 0; j < 4; ++j) {
        int idx = base + threadIdx.x * 4 + j;
        if (idx < total) s += counts[idx];
    }
    sh[threadIdx.x] = s;
    __syncthreads();
    for (int off = 128; off > 0; off >>= 1) {
        if (threadIdx.x < off) sh[threadIdx.x] += sh[threadIdx.x + off];
        __syncthreads();
    }
    if (threadIdx.x == 0) bsum[blockIdx.x] = sh[0];
}

__global__ void k_scan2(int* __restrict__ bsum, int nb) {
    __shared__ int sh[128];
    int t = threadIdx.x;
    int v = (t < nb) ? bsum[t] : 0;
    sh[t] = v;
    __syncthreads();
    for (int off = 1; off < 128; off <<= 1) {
        int u = 0;
        if (t >= off) u = sh[t - off];
        __syncthreads();
        sh[t] += u;
        __syncthreads();
    }
    if (t < nb) bsum[t] = sh[t] - v;  // exclusive
}

__global__ __launch_bounds__(TPB) void k_scan3(const int* __restrict__ counts, const int* __restrict__ bsum,
                                               int* __restrict__ offs, int total) {
    __shared__ int sh[TPB];
    int base = blockIdx.x * 1024;
    int v[4];
    int s = 0;
#pragma unroll
    for (int j = 0; j < 4; ++j) {
        int idx = base + threadIdx.x * 4 + j;
        v[j] = (idx < total) ? counts[idx] : 0;
        s += v[j];
    }
    sh[threadIdx.x] = s;
    __syncthreads();
    for (int off = 1; off < TPB; off <<= 1) {
        int t = 0;
        if (threadIdx.x >= off) t = sh[threadIdx.x - off];
        __syncthreads();
        sh[threadIdx.x] += t;
        __syncthreads();
    }
    int pre = bsum[blockIdx.x] + sh[threadIdx.x] - s;
#pragma unroll
    for (int j = 0; j < 4; ++j) {
        int idx = base + threadIdx.x * 4 + j;
        if (idx < total) { offs[idx] = pre; pre += v[j]; }
    }
}

__global__ __launch_bounds__(TPB) void k_scatter(const int* __restrict__ src, const int* __restrict__ dst,
                                                 const int* __restrict__ rank, const int* __restrict__ offs,
                                                 int* __restrict__ csr_src, int E) {
    int i = blockIdx.x * blockDim.x + threadIdx.x;
    if (i < E) csr_src[offs[dst[i]] + rank[i]] = src[i];
}

// ---------------- R = rho_w @ W0_pe ; cvec = rho_b @ W0_pe ----------------

__global__ __launch_bounds__(TPB) void k_rinit(const float* __restrict__ rho_w, const float* __restrict__ rho_b,
                                               const float* __restrict__ W0, float* __restrict__ R,
                                               float* __restrict__ cvec) {
    const float* Wpe = W0 + 128 * 64;  // rows 128..159 of W0
    int tid = threadIdx.x;
    for (int idx = tid; idx < 64 * 64; idx += TPB) {
        int r = idx >> 6, cc = idx & 63;
        float s = 0.f;
#pragma unroll
        for (int k = 0; k < 32; ++k) s = fmaf(rho_w[r * 32 + k], Wpe[k * 64 + cc], s);
        R[idx] = s;
    }
    if (tid < 64) {
        float s = 0.f;
#pragma unroll
        for (int k = 0; k < 32; ++k) s = fmaf(rho_b[k], Wpe[k * 64 + tid], s);
        cvec[tid] = s;
    }
}

// ---------------- fused SignNet ----------------

__global__ __launch_bounds__(TPB) void k_sign(const float* __restrict__ eig,
                                              const float* __restrict__ w1, const float* __restrict__ b1,
                                              const float* __restrict__ w2, const float* __restrict__ b2,
                                              ushort* __restrict__ S, int M) {
    __shared__ float eigS[64][9];
    __shared__ float w1s[512];
    __shared__ float b1s[64];
    __shared__ float Ap[64][65];
    __shared__ float Aq[64][65];
    __shared__ float Ws[64][64];
    const int tid = threadIdx.x;
    const int row0 = blockIdx.x * 64;

    for (int i = tid; i < 512; i += TPB) w1s[i] = w1[i];
    if (tid < 64) b1s[tid] = b1[tid];
    for (int i = tid; i < 1024; i += TPB) {
        float4 v = *(const float4*)(w2 + i * 4);
        Ws[0][i * 4 + 0] = v.x; Ws[0][i * 4 + 1] = v.y; Ws[0][i * 4 + 2] = v.z; Ws[0][i * 4 + 3] = v.w;
    }
    {
        int idx = tid * 2;
        int r = idx >> 3, c = idx & 7;
        int row = row0 + r; int rowc = row < M ? row : M - 1;
        float2 v = *(const float2*)(eig + (size_t)rowc * 8 + c);
        eigS[r][c] = v.x; eigS[r][c + 1] = v.y;
    }
    __syncthreads();

    {
        int r = tid >> 2, csub = tid & 3;
        float ev[8];
#pragma unroll
        for (int k = 0; k < 8; ++k) ev[k] = eigS[r][k];
#pragma unroll
        for (int c0 = 0; c0 < 16; ++c0) {
            int c = csub * 16 + c0;
            float t = 0.f;
#pragma unroll
            for (int k = 0; k < 8; ++k) t = fmaf(ev[k], w1s[k * 64 + c], t);
            float bb = b1s[c];
            Ap[c][r] = fmaxf(t + bb, 0.f);
            Aq[c][r] = fmaxf(bb - t, 0.f);
        }
    }
    __syncthreads();

    const int ty = tid >> 4, tx = tid & 15;
    float accp[4][4] = {{0.f}}, accq[4][4] = {{0.f}};
#pragma unroll 8
    for (int kk = 0; kk < 64; ++kk) {
        float ap[4], aq[4], bw[4];
#pragma unroll
        for (int i = 0; i < 4; ++i) { ap[i] = Ap[kk][ty * 4 + i]; aq[i] = Aq[kk][ty * 4 + i]; }
#pragma unroll
        for (int j = 0; j < 4; ++j) bw[j] = Ws[kk][tx * 4 + j];
#pragma unroll
        for (int i = 0; i < 4; ++i)
#pragma unroll
            for (int j = 0; j < 4; ++j) {
                accp[i][j] = fmaf(ap[i], bw[j], accp[i][j]);
                accq[i][j] = fmaf(aq[i], bw[j], accq[i][j]);
            }
    }
#pragma unroll
    for (int i = 0; i < 4; ++i) {
        int row = row0 + ty * 4 + i;
        if (row >= M) continue;
        ushort4 o;
        ushort* op = (ushort*)&o;
#pragma unroll
        for (int j = 0; j < 4; ++j) {
            int col = tx * 4 + j;
            float bb = b2[col];
            float v = fmaxf(accp[i][j] + bb, 0.f) + fmaxf(accq[i][j] + bb, 0.f);
            op[j] = f2b(v);
        }
        *(ushort4*)(S + (size_t)row * 64 + tx * 4) = o;
    }
}

// ---------------- main GEMM + fused alpha dot products ----------------

#define BM 64
#define BK 16

__global__ __launch_bounds__(TPB) void k_mm(const float* __restrict__ A1, int K1,
                                            const ushort* __restrict__ A2, int K2,
                                            const float* __restrict__ Wa, const float* __restrict__ Wb,
                                            const float* __restrict__ bias,
                                            const float* __restrict__ a_s, const float* __restrict__ a_d,
                                            float2* __restrict__ as2, float2* __restrict__ ad2,
                                            ushort* __restrict__ out, int M) {
    __shared__ float As[BK][BM + 4];
    __shared__ float Bs[BK][64];
    const int tid = threadIdx.x;
    const int row0 = blockIdx.x * BM;
    const int K = K1 + K2;
    const int ty = tid >> 4, tx = tid & 15;
    float acc[4][4] = {{0.f}};

    for (int k0 = 0; k0 < K; k0 += BK) {
        {
            int r = tid >> 2;
            int cq = (tid & 3) * 4;
            int row = row0 + r;
            int rowc = row < M ? row : M - 1;
            int c = k0 + cq;
            float4 v;
            if (c < K1) {
                v = *(const float4*)(A1 + (size_t)rowc * K1 + c);
            } else {
                const ushort* p = A2 + (size_t)rowc * K2 + (c - K1);
                ushort4 u = *(const ushort4*)p;
                v = make_float4(b2f(u.x), b2f(u.y), b2f(u.z), b2f(u.w));
            }
            As[cq + 0][r] = v.x; As[cq + 1][r] = v.y; As[cq + 2][r] = v.z; As[cq + 3][r] = v.w;
        }
        {
            int rr = tid >> 4;
            int cq2 = (tid & 15) * 4;
            int kk = k0 + rr;
            const float* Wrow = (kk < K1) ? (Wa + (size_t)kk * 64) : (Wb + (size_t)(kk - K1) * 64);
            float4 wv = *(const float4*)(Wrow + cq2);
            Bs[rr][cq2 + 0] = wv.x; Bs[rr][cq2 + 1] = wv.y; Bs[rr][cq2 + 2] = wv.z; Bs[rr][cq2 + 3] = wv.w;
        }
        __syncthreads();
#pragma unroll
        for (int kk = 0; kk < BK; ++kk) {
            float a[4], bw[4];
#pragma unroll
            for (int i = 0; i < 4; ++i) a[i] = As[kk][ty * 4 + i];
#pragma unroll
            for (int j = 0; j < 4; ++j) bw[j] = Bs[kk][tx * 4 + j];
#pragma unroll
            for (int i = 0; i < 4; ++i)
#pragma unroll
                for (int j = 0; j < 4; ++j)
                    acc[i][j] = fmaf(a[i], bw[j], acc[i][j]);
        }
        __syncthreads();
    }

    float s_acc[4] = {0.f, 0.f, 0.f, 0.f}, d_acc[4] = {0.f, 0.f, 0.f, 0.f};
#pragma unroll
    for (int i = 0; i < 4; ++i) {
#pragma unroll
        for (int j = 0; j < 4; ++j) {
            int col = tx * 4 + j;
            float v = acc[i][j];
            if (bias) v += bias[col];
            acc[i][j] = v;
            s_acc[i] = fmaf(v, a_s[col], s_acc[i]);
            d_acc[i] = fmaf(v, a_d[col], d_acc[i]);
        }
    }
#pragma unroll
    for (int m = 1; m <= 4; m <<= 1) {
#pragma unroll
        for (int i = 0; i < 4; ++i) {
            s_acc[i] += __shfl_xor(s_acc[i], m);
            d_acc[i] += __shfl_xor(d_acc[i], m);
        }
    }
    float s_oth[4], d_oth[4];
#pragma unroll
    for (int i = 0; i < 4; ++i) {
        s_oth[i] = __shfl_xor(s_acc[i], 8);
        d_oth[i] = __shfl_xor(d_acc[i], 8);
    }
#pragma unroll
    for (int i = 0; i < 4; ++i) {
        int row = row0 + ty * 4 + i;
        if (row >= M) continue;
        ushort4 o;
        ushort* op = (ushort*)&o;
#pragma unroll
        for (int j = 0; j < 4; ++j) op[j] = f2b(acc[i][j]);
        *(ushort4*)(out + (size_t)row * 64 + tx * 4) = o;
        if (tx == 0) {
            as2[row] = make_float2(s_acc[i], s_oth[i]);
            ad2[row] = make_float2(d_acc[i], d_oth[i]);
        }
    }
}

// ---------------- GAT aggregation: wave per dst, pair-edge layout ----------------
// lanes 0-31 process even edges, 32-63 odd edges; each lane owns 2 adjacent channels
// (one 4B uint = 2 bf16 per gather). Per-lane-source shuffles (ds_bpermute).
// den via wave-reduction once per 64-edge chunk (order-free sum).
// DO_LN=0: bf16 output (ushort*); DO_LN=1: fp32 output + LayerNorm (float*).

template <int DO_LN>
__global__ __launch_bounds__(TPB) void k_agg(const int* __restrict__ offs, const int* __restrict__ csr_src,
                                             const ushort* __restrict__ hb,
                                             const float2* __restrict__ as2,
                                             const float2* __restrict__ ad2,
                                             const float* __restrict__ bias,
                                             const float* __restrict__ ln_g,
                                             const float* __restrict__ ln_b,
                                             void* __restrict__ out_v, int M) {
    int w = (blockIdx.x * blockDim.x + threadIdx.x) >> 6;
    int lane = threadIdx.x & 63;
    if (w >= M) return;
    const int cidx = lane & 31;        // channel pair index: channels 2*cidx, 2*cidx+1
    const int half = lane >> 5;        // 0: even edges, 1: odd edges
    const int head = cidx >> 4;        // head of both owned channels
    const uint32_t laneoff = (uint32_t)(cidx * 2);  // element offset within row

    float2 adv = ad2[w];
    int beg = offs[w], end = offs[w + 1];
    float a0 = 0.f, a1 = 0.f;          // channel accumulators (this half's edges)
    float den0 = 0.f, den1 = 0.f;

    for (int base = beg; base < end; base += 64) {
        int nk = end - base;
        if (nk > 64) nk = 64;
        int sidx = csr_src[base + (lane < nk ? lane : 0)];
        float2 av = as2[sidx];
        float e0 = av.x + adv.x; e0 = e0 > 0.f ? e0 : 0.2f * e0;
        float e1 = av.y + adv.y; e1 = e1 > 0.f ? e1 : 0.2f * e1;
        float p0 = __expf(e0), p1 = __expf(e1);
        if (lane >= nk) { p0 = 0.f; p1 = 0.f; }
        // den: order-free wave sum (once per chunk)
        float t0 = p0, t1 = p1;
#pragma unroll
        for (int m = 1; m <= 32; m <<= 1) {
            t0 += __shfl_xor(t0, m);
            t1 += __shfl_xor(t1, m);
        }
        den0 += t0; den1 += t1;
        // pair loop: 2 edges per iteration (lane half selects which)
        int npair = (nk + 1) >> 1;
        for (int jp = 0; jp < npair; ++jp) {
            int srcl = jp * 2 + half;                 // per-lane source lane
            int s = __shfl(sidx, srcl);
            float q0 = __shfl(p0, srcl);
            float q1 = __shfl(p1, srcl);
            float q = head ? q1 : q0;                 // 0 for invalid odd tail edge
            uint32_t u = *(const uint32_t*)(hb + (uint32_t)s * 64u + laneoff);
            a0 = fmaf(q, b2f_lo(u), a0);
            a1 = fmaf(q, b2f_hi(u), a1);
        }
    }
    // combine the two edge-halves: lanes l and l+32 hold the same channels
    a0 += __shfl_xor(a0, 32);
    a1 += __shfl_xor(a1, 32);

    float den = (head ? den1 : den0) + 1e-16f;
    float2 bb = *(const float2*)(bias + cidx * 2);
    float o0 = a0 / den + bb.x;
    float o1 = a1 / den + bb.y;
    o0 = o0 > 0.f ? o0 : expm1f(o0);
    o1 = o1 > 0.f ? o1 : expm1f(o1);

    if (DO_LN) {
        // every channel is present twice in the wave (lanes l and l+32) -> /128
        float mu = o0 + o1;
#pragma unroll
        for (int m = 1; m <= 32; m <<= 1) mu += __shfl_xor(mu, m);
        mu *= (1.f / 128.f);
        float dv = (o0 - mu) * (o0 - mu) + (o1 - mu) * (o1 - mu);
#pragma unroll
        for (int m = 1; m <= 32; m <<= 1) dv += __shfl_xor(dv, m);
        dv *= (1.f / 128.f);
        float rs = rsqrtf(dv + 1e-5f);
        float2 g = *(const float2*)(ln_g + cidx * 2);
        float2 b = *(const float2*)(ln_b + cidx * 2);
        o0 = (o0 - mu) * rs * g.x + b.x;
        o1 = (o1 - mu) * rs * g.y + b.y;
        if (lane < 32) {
            float2* out = (float2*)out_v;
            out[(size_t)w * 32 + cidx] = make_float2(o0, o1);
        }
    } else {
        if (lane < 32) {
            uint32_t pk = (uint32_t)f2b(o0) | ((uint32_t)f2b(o1) << 16);
            uint32_t* out = (uint32_t*)out_v;
            out[(size_t)w * 32 + cidx] = pk;
        }
    }
}

// ---------------- launcher ----------------

extern "C" void kernel_launch(void* const* d_in, const int* in_sizes, int n_in,
                              void* d_out, int out_size, void* d_ws, size_t ws_size,
                              hipStream_t stream) {
    const float* x      = (const float*)d_in[0];
    const float* eig    = (const float*)d_in[1];
    const int*   ei     = (const int*)d_in[2];
    const float* phi_w1 = (const float*)d_in[3];
    const float* phi_b1 = (const float*)d_in[4];
    const float* phi_w2 = (const float*)d_in[5];
    const float* phi_b2 = (const float*)d_in[6];
    const float* rho_w  = (const float*)d_in[7];
    const float* rho_b  = (const float*)d_in[8];
    const float* W0     = (const float*)d_in[9];
    const float* asrc0  = (const float*)d_in[10];
    const float* adst0  = (const float*)d_in[11];
    const float* b0     = (const float*)d_in[12];
    const float* W1     = (const float*)d_in[13];
    const float* asrc1  = (const float*)d_in[14];
    const float* adst1  = (const float*)d_in[15];
    const float* b1     = (const float*)d_in[16];
    const float* ln_g   = (const float*)d_in[17];
    const float* ln_b   = (const float*)d_in[18];

    const int N = in_sizes[0] / 128;
    const int E = in_sizes[2] / 2;
    const int* esrc = ei;
    const int* edst = ei + E;

    auto alignup = [](size_t v) { return (v + 255) & ~(size_t)255; };
    char* w = (char*)d_ws;
    int* counts = (int*)w; w += alignup((size_t)(N + 1) * 4);
    int* offs   = (int*)w; w += alignup((size_t)(N + 1) * 4);
    int* rank   = (int*)w; w += alignup((size_t)E * 4);
    int* bsum   = (int*)w; w += alignup(4096);
    int* csr    = (int*)w; w += alignup((size_t)E * 4);
    ushort* Sb  = (ushort*)w; w += alignup((size_t)N * 64 * 2);  // SignNet output (bf16)
    ushort* hb  = (ushort*)w; w += alignup((size_t)N * 64 * 2);  // h0 / h1 bf16
    ushort* g0b = (ushort*)w; w += alignup((size_t)N * 64 * 2);  // layer-0 output bf16
    float2* as2 = (float2*)w; w += alignup((size_t)N * 8);
    float2* ad2 = (float2*)w; w += alignup((size_t)N * 8);
    float* R    = (float*)w; w += alignup(64 * 64 * 4);
    float* cvec = (float*)w; w += alignup(64 * 4);

    // ---- CSR build ----
    hipMemsetAsync(counts, 0, (size_t)(N + 1) * 4, stream);
    int ge = (E + TPB - 1) / TPB;
    k_countrank<<<ge, TPB, 0, stream>>>(edst, counts, rank, E);
    int nb = (N + 1 + 1023) / 1024;
    k_scan1<<<nb, TPB, 0, stream>>>(counts, bsum, N + 1);
    k_scan2<<<1, 128, 0, stream>>>(bsum, nb);
    k_scan3<<<nb, TPB, 0, stream>>>(counts, bsum, offs, N + 1);
    k_scatter<<<ge, TPB, 0, stream>>>(esrc, edst, rank, offs, csr, E);

    k_rinit<<<1, TPB, 0, stream>>>(rho_w, rho_b, W0, R, cvec);

    int gM = (N + BM - 1) / BM;
    // ---- SignNet (fused phi1+phi2) ----
    k_sign<<<gM, TPB, 0, stream>>>(eig, phi_w1, phi_b1, phi_w2, phi_b2, Sb, N);

    // ---- GAT layer 0: h0 = x@W0[:128] + S@R + cvec -> hb (bf16), fused alpha ----
    k_mm<<<gM, TPB, 0, stream>>>(x, 128, Sb, 64, W0, R, cvec, asrc0, adst0, as2, ad2, hb, N);
    int ga = (N + 3) / 4;
    k_agg<0><<<ga, TPB, 0, stream>>>(offs, csr, hb, as2, ad2, b0, nullptr, nullptr, g0b, N);

    // ---- GAT layer 1: h1 = g0@W1 -> hb (bf16), fused alpha ----
    k_mm<<<gM, TPB, 0, stream>>>(nullptr, 0, g0b, 64, nullptr, W1, nullptr, asrc1, adst1, as2, ad2, hb, N);
    k_agg<1><<<ga, TPB, 0, stream>>>(offs, csr, hb, as2, ad2, b1, ln_g, ln_b, d_out, N);

    (void)n_in; (void)ws_size; (void)out_size;
}

// Round 7
// 336.592 us; speedup vs baseline: 1.1277x; 1.1277x over previous
//
#include <hip/hip_runtime.h>
#include <cstdint>
#include <cstddef>
#include <cstring>

#define TPB 256

__device__ __forceinline__ ushort f2b(float f) {
    union { float f; uint32_t u; } v; v.f = f;
    uint32_t r = (v.u + 0x7FFFu + ((v.u >> 16) & 1u)) >> 16;
    return (ushort)r;
}
__device__ __forceinline__ float b2f(ushort h) {
    union { uint32_t u; float f; } v; v.u = ((uint32_t)h) << 16;
    return v.f;
}
__device__ __forceinline__ float b2f_lo(uint32_t u) {
    union { uint32_t u; float f; } v; v.u = u << 16;
    return v.f;
}
__device__ __forceinline__ float b2f_hi(uint32_t u) {
    union { uint32_t u; float f; } v; v.u = u & 0xFFFF0000u;
    return v.f;
}
__device__ __forceinline__ float f16lo2f(uint32_t u) {
    union { ushort s; _Float16 h; } v; v.s = (ushort)u;
    return (float)v.h;
}
__device__ __forceinline__ uint32_t pack_f16x2(float p0, float p1) {
    auto hp = __builtin_amdgcn_cvt_pkrtz(p0, p1);  // __fp16 ext_vector(2)
    uint32_t pk;
    __builtin_memcpy(&pk, &hp, 4);
    return pk;
}

// ---------------- CSR build (single-atomic: rank folded into count) ----------------

__global__ __launch_bounds__(TPB) void k_countrank(const int* __restrict__ dst, int* __restrict__ counts,
                                                   int* __restrict__ rank, int E) {
    int i = blockIdx.x * blockDim.x + threadIdx.x;
    if (i < E) rank[i] = atomicAdd(&counts[dst[i]], 1);
}

__global__ __launch_bounds__(TPB) void k_scan1(const int* __restrict__ counts, int* __restrict__ bsum, int total) {
    __shared__ int sh[TPB];
    int base = blockIdx.x * 1024;
    int s = 0;
#pragma unroll
    for (int j = 0; j < 4; ++j) {
        int idx = base + threadIdx.x * 4 + j;
        if (idx < total) s += counts[idx];
    }
    sh[threadIdx.x] = s;
    __syncthreads();
    for (int off = 128; off > 0; off >>= 1) {
        if (threadIdx.x < off) sh[threadIdx.x] += sh[threadIdx.x + off];
        __syncthreads();
    }
    if (threadIdx.x == 0) bsum[blockIdx.x] = sh[0];
}

__global__ void k_scan2(int* __restrict__ bsum, int nb) {
    __shared__ int sh[128];
    int t = threadIdx.x;
    int v = (t < nb) ? bsum[t] : 0;
    sh[t] = v;
    __syncthreads();
    for (int off = 1; off < 128; off <<= 1) {
        int u = 0;
        if (t >= off) u = sh[t - off];
        __syncthreads();
        sh[t] += u;
        __syncthreads();
    }
    if (t < nb) bsum[t] = sh[t] - v;  // exclusive
}

__global__ __launch_bounds__(TPB) void k_scan3(const int* __restrict__ counts, const int* __restrict__ bsum,
                                               int* __restrict__ offs, int total) {
    __shared__ int sh[TPB];
    int base = blockIdx.x * 1024;
    int v[4];
    int s = 0;
#pragma unroll
    for (int j = 0; j < 4; ++j) {
        int idx = base + threadIdx.x * 4 + j;
        v[j] = (idx < total) ? counts[idx] : 0;
        s += v[j];
    }
    sh[threadIdx.x] = s;
    __syncthreads();
    for (int off = 1; off < TPB; off <<= 1) {
        int t = 0;
        if (threadIdx.x >= off) t = sh[threadIdx.x - off];
        __syncthreads();
        sh[threadIdx.x] += t;
        __syncthreads();
    }
    int pre = bsum[blockIdx.x] + sh[threadIdx.x] - s;
#pragma unroll
    for (int j = 0; j < 4; ++j) {
        int idx = base + threadIdx.x * 4 + j;
        if (idx < total) { offs[idx] = pre; pre += v[j]; }
    }
}

__global__ __launch_bounds__(TPB) void k_scatter(const int* __restrict__ src, const int* __restrict__ dst,
                                                 const int* __restrict__ rank, const int* __restrict__ offs,
                                                 int* __restrict__ csr_src, int E) {
    int i = blockIdx.x * blockDim.x + threadIdx.x;
    if (i < E) csr_src[offs[dst[i]] + rank[i]] = src[i];
}

// ---------------- R = rho_w @ W0_pe ; cvec = rho_b @ W0_pe ----------------

__global__ __launch_bounds__(TPB) void k_rinit(const float* __restrict__ rho_w, const float* __restrict__ rho_b,
                                               const float* __restrict__ W0, float* __restrict__ R,
                                               float* __restrict__ cvec) {
    const float* Wpe = W0 + 128 * 64;  // rows 128..159 of W0
    int tid = threadIdx.x;
    for (int idx = tid; idx < 64 * 64; idx += TPB) {
        int r = idx >> 6, cc = idx & 63;
        float s = 0.f;
#pragma unroll
        for (int k = 0; k < 32; ++k) s = fmaf(rho_w[r * 32 + k], Wpe[k * 64 + cc], s);
        R[idx] = s;
    }
    if (tid < 64) {
        float s = 0.f;
#pragma unroll
        for (int k = 0; k < 32; ++k) s = fmaf(rho_b[k], Wpe[k * 64 + tid], s);
        cvec[tid] = s;
    }
}

// ---------------- fused SignNet ----------------

__global__ __launch_bounds__(TPB) void k_sign(const float* __restrict__ eig,
                                              const float* __restrict__ w1, const float* __restrict__ b1,
                                              const float* __restrict__ w2, const float* __restrict__ b2,
                                              ushort* __restrict__ S, int M) {
    __shared__ float eigS[64][9];
    __shared__ float w1s[512];
    __shared__ float b1s[64];
    __shared__ float Ap[64][65];
    __shared__ float Aq[64][65];
    __shared__ float Ws[64][64];
    const int tid = threadIdx.x;
    const int row0 = blockIdx.x * 64;

    for (int i = tid; i < 512; i += TPB) w1s[i] = w1[i];
    if (tid < 64) b1s[tid] = b1[tid];
    for (int i = tid; i < 1024; i += TPB) {
        float4 v = *(const float4*)(w2 + i * 4);
        Ws[0][i * 4 + 0] = v.x; Ws[0][i * 4 + 1] = v.y; Ws[0][i * 4 + 2] = v.z; Ws[0][i * 4 + 3] = v.w;
    }
    {
        int idx = tid * 2;
        int r = idx >> 3, c = idx & 7;
        int row = row0 + r; int rowc = row < M ? row : M - 1;
        float2 v = *(const float2*)(eig + (size_t)rowc * 8 + c);
        eigS[r][c] = v.x; eigS[r][c + 1] = v.y;
    }
    __syncthreads();

    {
        int r = tid >> 2, csub = tid & 3;
        float ev[8];
#pragma unroll
        for (int k = 0; k < 8; ++k) ev[k] = eigS[r][k];
#pragma unroll
        for (int c0 = 0; c0 < 16; ++c0) {
            int c = csub * 16 + c0;
            float t = 0.f;
#pragma unroll
            for (int k = 0; k < 8; ++k) t = fmaf(ev[k], w1s[k * 64 + c], t);
            float bb = b1s[c];
            Ap[c][r] = fmaxf(t + bb, 0.f);
            Aq[c][r] = fmaxf(bb - t, 0.f);
        }
    }
    __syncthreads();

    const int ty = tid >> 4, tx = tid & 15;
    float accp[4][4] = {{0.f}}, accq[4][4] = {{0.f}};
#pragma unroll 8
    for (int kk = 0; kk < 64; ++kk) {
        float ap[4], aq[4], bw[4];
#pragma unroll
        for (int i = 0; i < 4; ++i) { ap[i] = Ap[kk][ty * 4 + i]; aq[i] = Aq[kk][ty * 4 + i]; }
#pragma unroll
        for (int j = 0; j < 4; ++j) bw[j] = Ws[kk][tx * 4 + j];
#pragma unroll
        for (int i = 0; i < 4; ++i)
#pragma unroll
            for (int j = 0; j < 4; ++j) {
                accp[i][j] = fmaf(ap[i], bw[j], accp[i][j]);
                accq[i][j] = fmaf(aq[i], bw[j], accq[i][j]);
            }
    }
#pragma unroll
    for (int i = 0; i < 4; ++i) {
        int row = row0 + ty * 4 + i;
        if (row >= M) continue;
        ushort4 o;
        ushort* op = (ushort*)&o;
#pragma unroll
        for (int j = 0; j < 4; ++j) {
            int col = tx * 4 + j;
            float bb = b2[col];
            float v = fmaxf(accp[i][j] + bb, 0.f) + fmaxf(accq[i][j] + bb, 0.f);
            op[j] = f2b(v);
        }
        *(ushort4*)(S + (size_t)row * 64 + tx * 4) = o;
    }
}

// ---------------- main GEMM + fused alpha dot products ----------------

#define BM 64
#define BK 16

__global__ __launch_bounds__(TPB) void k_mm(const float* __restrict__ A1, int K1,
                                            const ushort* __restrict__ A2, int K2,
                                            const float* __restrict__ Wa, const float* __restrict__ Wb,
                                            const float* __restrict__ bias,
                                            const float* __restrict__ a_s, const float* __restrict__ a_d,
                                            float2* __restrict__ as2, float2* __restrict__ ad2,
                                            ushort* __restrict__ out, int M) {
    __shared__ float As[BK][BM + 4];
    __shared__ float Bs[BK][64];
    const int tid = threadIdx.x;
    const int row0 = blockIdx.x * BM;
    const int K = K1 + K2;
    const int ty = tid >> 4, tx = tid & 15;
    float acc[4][4] = {{0.f}};

    for (int k0 = 0; k0 < K; k0 += BK) {
        {
            int r = tid >> 2;
            int cq = (tid & 3) * 4;
            int row = row0 + r;
            int rowc = row < M ? row : M - 1;
            int c = k0 + cq;
            float4 v;
            if (c < K1) {
                v = *(const float4*)(A1 + (size_t)rowc * K1 + c);
            } else {
                const ushort* p = A2 + (size_t)rowc * K2 + (c - K1);
                ushort4 u = *(const ushort4*)p;
                v = make_float4(b2f(u.x), b2f(u.y), b2f(u.z), b2f(u.w));
            }
            As[cq + 0][r] = v.x; As[cq + 1][r] = v.y; As[cq + 2][r] = v.z; As[cq + 3][r] = v.w;
        }
        {
            int rr = tid >> 4;
            int cq2 = (tid & 15) * 4;
            int kk = k0 + rr;
            const float* Wrow = (kk < K1) ? (Wa + (size_t)kk * 64) : (Wb + (size_t)(kk - K1) * 64);
            float4 wv = *(const float4*)(Wrow + cq2);
            Bs[rr][cq2 + 0] = wv.x; Bs[rr][cq2 + 1] = wv.y; Bs[rr][cq2 + 2] = wv.z; Bs[rr][cq2 + 3] = wv.w;
        }
        __syncthreads();
#pragma unroll
        for (int kk = 0; kk < BK; ++kk) {
            float a[4], bw[4];
#pragma unroll
            for (int i = 0; i < 4; ++i) a[i] = As[kk][ty * 4 + i];
#pragma unroll
            for (int j = 0; j < 4; ++j) bw[j] = Bs[kk][tx * 4 + j];
#pragma unroll
            for (int i = 0; i < 4; ++i)
#pragma unroll
                for (int j = 0; j < 4; ++j)
                    acc[i][j] = fmaf(a[i], bw[j], acc[i][j]);
        }
        __syncthreads();
    }

    float s_acc[4] = {0.f, 0.f, 0.f, 0.f}, d_acc[4] = {0.f, 0.f, 0.f, 0.f};
#pragma unroll
    for (int i = 0; i < 4; ++i) {
#pragma unroll
        for (int j = 0; j < 4; ++j) {
            int col = tx * 4 + j;
            float v = acc[i][j];
            if (bias) v += bias[col];
            acc[i][j] = v;
            s_acc[i] = fmaf(v, a_s[col], s_acc[i]);
            d_acc[i] = fmaf(v, a_d[col], d_acc[i]);
        }
    }
#pragma unroll
    for (int m = 1; m <= 4; m <<= 1) {
#pragma unroll
        for (int i = 0; i < 4; ++i) {
            s_acc[i] += __shfl_xor(s_acc[i], m);
            d_acc[i] += __shfl_xor(d_acc[i], m);
        }
    }
    float s_oth[4], d_oth[4];
#pragma unroll
    for (int i = 0; i < 4; ++i) {
        s_oth[i] = __shfl_xor(s_acc[i], 8);
        d_oth[i] = __shfl_xor(d_acc[i], 8);
    }
#pragma unroll
    for (int i = 0; i < 4; ++i) {
        int row = row0 + ty * 4 + i;
        if (row >= M) continue;
        ushort4 o;
        ushort* op = (ushort*)&o;
#pragma unroll
        for (int j = 0; j < 4; ++j) op[j] = f2b(acc[i][j]);
        *(ushort4*)(out + (size_t)row * 64 + tx * 4) = o;
        if (tx == 0) {
            as2[row] = make_float2(s_acc[i], s_oth[i]);
            ad2[row] = make_float2(d_acc[i], d_oth[i]);
        }
    }
}

// ---------------- GAT aggregation: wave per dst, 4 edges/iteration ----------------
// wave = 4 groups x 16 lanes. Per chunk of <=64 edges: each lane stages one edge
// (sidx + p packed as f16x2 via cvt_pkrtz in its home lane); den by wave reduction.
// Inner loop: group g gathers edge (j+g)'s 128B row as one uint2 (16 lanes x 8B);
// sidx/pk fetched by ds_bpermute. Tail lanes carry p=0 so clamped sources are
// harmless. Epilogue folds the 4 group accumulators with 2 shfl_xor per channel.
// DO_LN=0: bf16 out (ushort*); DO_LN=1: fp32 out + LayerNorm (float*).

template <int DO_LN>
__global__ __launch_bounds__(TPB) void k_agg(const int* __restrict__ offs, const int* __restrict__ csr_src,
                                             const ushort* __restrict__ hb,
                                             const float2* __restrict__ as2,
                                             const float2* __restrict__ ad2,
                                             const float* __restrict__ bias,
                                             const float* __restrict__ ln_g,
                                             const float* __restrict__ ln_b,
                                             void* __restrict__ out_v, int M) {
    int w = (blockIdx.x * blockDim.x + threadIdx.x) >> 6;
    int lane = threadIdx.x & 63;
    if (w >= M) return;
    const int sub = lane & 15;       // lane within group
    const int grp = lane >> 4;       // group 0..3
    const int c0 = sub * 4;          // first of 4 owned channels
    const int head = sub >> 3;       // head of all 4 owned channels
    const int hshift = head << 4;    // 0 or 16

    float2 adv = ad2[w];
    int beg = offs[w], end = offs[w + 1];
    float a0 = 0.f, a1 = 0.f, a2 = 0.f, a3 = 0.f;
    float den0 = 0.f, den1 = 0.f;

    for (int base = beg; base < end; base += 64) {
        int nk = end - base;
        if (nk > 64) nk = 64;
        // ---- stage: one edge per lane ----
        int sidx = csr_src[base + (lane < nk ? lane : 0)];
        float2 av = as2[sidx];
        float e0 = av.x + adv.x; e0 = e0 > 0.f ? e0 : 0.2f * e0;
        float e1 = av.y + adv.y; e1 = e1 > 0.f ? e1 : 0.2f * e1;
        float p0 = __expf(e0), p1 = __expf(e1);
        if (lane >= nk) { p0 = 0.f; p1 = 0.f; }
        // den: order-free wave reduction
        float t0 = p0, t1 = p1;
#pragma unroll
        for (int m = 1; m <= 32; m <<= 1) {
            t0 += __shfl_xor(t0, m);
            t1 += __shfl_xor(t1, m);
        }
        den0 += t0; den1 += t1;
        uint32_t pk = pack_f16x2(p0, p1);

        // ---- inner: 8 edges per iteration (two 4-edge waves in flight) ----
        int j = 0;
        for (; j + 8 <= nk; j += 8) {
            int srcA = (j + grp) << 2;
            int srcB = (j + 4 + grp) << 2;
            int sA = __builtin_amdgcn_ds_bpermute(srcA, sidx);
            int sB = __builtin_amdgcn_ds_bpermute(srcB, sidx);
            uint32_t pA = (uint32_t)__builtin_amdgcn_ds_bpermute(srcA, (int)pk);
            uint32_t pB = (uint32_t)__builtin_amdgcn_ds_bpermute(srcB, (int)pk);
            uint2 uA = *(const uint2*)(hb + (size_t)(uint32_t)sA * 64u + c0);
            uint2 uB = *(const uint2*)(hb + (size_t)(uint32_t)sB * 64u + c0);
            float qA = f16lo2f(pA >> hshift);
            float qB = f16lo2f(pB >> hshift);
            a0 = fmaf(qA, b2f_lo(uA.x), a0);
            a1 = fmaf(qA, b2f_hi(uA.x), a1);
            a2 = fmaf(qA, b2f_lo(uA.y), a2);
            a3 = fmaf(qA, b2f_hi(uA.y), a3);
            a0 = fmaf(qB, b2f_lo(uB.x), a0);
            a1 = fmaf(qB, b2f_hi(uB.x), a1);
            a2 = fmaf(qB, b2f_lo(uB.y), a2);
            a3 = fmaf(qB, b2f_hi(uB.y), a3);
        }
        for (; j < nk; j += 4) {
            int src = j + grp;
            if (src > 63) src = 63;          // clamp; p=0 there if >= nk
            int s = __builtin_amdgcn_ds_bpermute(src << 2, sidx);
            uint32_t pe = (uint32_t)__builtin_amdgcn_ds_bpermute(src << 2, (int)pk);
            uint2 u = *(const uint2*)(hb + (size_t)(uint32_t)s * 64u + c0);
            float q = f16lo2f(pe >> hshift);
            a0 = fmaf(q, b2f_lo(u.x), a0);
            a1 = fmaf(q, b2f_hi(u.x), a1);
            a2 = fmaf(q, b2f_lo(u.y), a2);
            a3 = fmaf(q, b2f_hi(u.y), a3);
        }
    }
    // fold the 4 groups (lanes l, l+16, l+32, l+48 share channel set)
    a0 += __shfl_xor(a0, 16); a0 += __shfl_xor(a0, 32);
    a1 += __shfl_xor(a1, 16); a1 += __shfl_xor(a1, 32);
    a2 += __shfl_xor(a2, 16); a2 += __shfl_xor(a2, 32);
    a3 += __shfl_xor(a3, 16); a3 += __shfl_xor(a3, 32);

    float den = (head ? den1 : den0) + 1e-16f;
    float inv = 1.f / den;
    float4 bb = *(const float4*)(bias + c0);
    float o0 = fmaf(a0, inv, bb.x);
    float o1 = fmaf(a1, inv, bb.y);
    float o2 = fmaf(a2, inv, bb.z);
    float o3 = fmaf(a3, inv, bb.w);
    o0 = o0 > 0.f ? o0 : expm1f(o0);
    o1 = o1 > 0.f ? o1 : expm1f(o1);
    o2 = o2 > 0.f ? o2 : expm1f(o2);
    o3 = o3 > 0.f ? o3 : expm1f(o3);

    if (DO_LN) {
        float mu = o0 + o1 + o2 + o3;
#pragma unroll
        for (int m = 1; m <= 8; m <<= 1) mu += __shfl_xor(mu, m);
        mu *= (1.f / 64.f);
        float dv = (o0 - mu) * (o0 - mu) + (o1 - mu) * (o1 - mu)
                 + (o2 - mu) * (o2 - mu) + (o3 - mu) * (o3 - mu);
#pragma unroll
        for (int m = 1; m <= 8; m <<= 1) dv += __shfl_xor(dv, m);
        dv *= (1.f / 64.f);
        float rs = rsqrtf(dv + 1e-5f);
        float4 g = *(const float4*)(ln_g + c0);
        float4 b = *(const float4*)(ln_b + c0);
        o0 = (o0 - mu) * rs * g.x + b.x;
        o1 = (o1 - mu) * rs * g.y + b.y;
        o2 = (o2 - mu) * rs * g.z + b.z;
        o3 = (o3 - mu) * rs * g.w + b.w;
        if (lane < 16) {
            float4* out = (float4*)out_v;
            out[(size_t)w * 16 + sub] = make_float4(o0, o1, o2, o3);
        }
    } else {
        if (lane < 16) {
            uint2 pk2;
            pk2.x = (uint32_t)f2b(o0) | ((uint32_t)f2b(o1) << 16);
            pk2.y = (uint32_t)f2b(o2) | ((uint32_t)f2b(o3) << 16);
            uint2* out = (uint2*)out_v;
            out[(size_t)w * 16 + sub] = pk2;
        }
    }
}

// ---------------- launcher ----------------

extern "C" void kernel_launch(void* const* d_in, const int* in_sizes, int n_in,
                              void* d_out, int out_size, void* d_ws, size_t ws_size,
                              hipStream_t stream) {
    const float* x      = (const float*)d_in[0];
    const float* eig    = (const float*)d_in[1];
    const int*   ei     = (const int*)d_in[2];
    const float* phi_w1 = (const float*)d_in[3];
    const float* phi_b1 = (const float*)d_in[4];
    const float* phi_w2 = (const float*)d_in[5];
    const float* phi_b2 = (const float*)d_in[6];
    const float* rho_w  = (const float*)d_in[7];
    const float* rho_b  = (const float*)d_in[8];
    const float* W0     = (const float*)d_in[9];
    const float* asrc0  = (const float*)d_in[10];
    const float* adst0  = (const float*)d_in[11];
    const float* b0     = (const float*)d_in[12];
    const float* W1     = (const float*)d_in[13];
    const float* asrc1  = (const float*)d_in[14];
    const float* adst1  = (const float*)d_in[15];
    const float* b1     = (const float*)d_in[16];
    const float* ln_g   = (const float*)d_in[17];
    const float* ln_b   = (const float*)d_in[18];

    const int N = in_sizes[0] / 128;
    const int E = in_sizes[2] / 2;
    const int* esrc = ei;
    const int* edst = ei + E;

    auto alignup = [](size_t v) { return (v + 255) & ~(size_t)255; };
    char* w = (char*)d_ws;
    int* counts = (int*)w; w += alignup((size_t)(N + 1) * 4);
    int* offs   = (int*)w; w += alignup((size_t)(N + 1) * 4);
    int* rank   = (int*)w; w += alignup((size_t)E * 4);
    int* bsum   = (int*)w; w += alignup(4096);
    int* csr    = (int*)w; w += alignup((size_t)E * 4);
    ushort* Sb  = (ushort*)w; w += alignup((size_t)N * 64 * 2);  // SignNet output (bf16)
    ushort* hb  = (ushort*)w; w += alignup((size_t)N * 64 * 2);  // h0 / h1 bf16
    ushort* g0b = (ushort*)w; w += alignup((size_t)N * 64 * 2);  // layer-0 output bf16
    float2* as2 = (float2*)w; w += alignup((size_t)N * 8);
    float2* ad2 = (float2*)w; w += alignup((size_t)N * 8);
    float* R    = (float*)w; w += alignup(64 * 64 * 4);
    float* cvec = (float*)w; w += alignup(64 * 4);

    // ---- CSR build ----
    (void)hipMemsetAsync(counts, 0, (size_t)(N + 1) * 4, stream);
    int ge = (E + TPB - 1) / TPB;
    k_countrank<<<ge, TPB, 0, stream>>>(edst, counts, rank, E);
    int nb = (N + 1 + 1023) / 1024;
    k_scan1<<<nb, TPB, 0, stream>>>(counts, bsum, N + 1);
    k_scan2<<<1, 128, 0, stream>>>(bsum, nb);
    k_scan3<<<nb, TPB, 0, stream>>>(counts, bsum, offs, N + 1);
    k_scatter<<<ge, TPB, 0, stream>>>(esrc, edst, rank, offs, csr, E);

    k_rinit<<<1, TPB, 0, stream>>>(rho_w, rho_b, W0, R, cvec);

    int gM = (N + BM - 1) / BM;
    // ---- SignNet (fused phi1+phi2) ----
    k_sign<<<gM, TPB, 0, stream>>>(eig, phi_w1, phi_b1, phi_w2, phi_b2, Sb, N);

    // ---- GAT layer 0: h0 = x@W0[:128] + S@R + cvec -> hb (bf16), fused alpha ----
    k_mm<<<gM, TPB, 0, stream>>>(x, 128, Sb, 64, W0, R, cvec, asrc0, adst0, as2, ad2, hb, N);
    int ga = (N + 3) / 4;
    k_agg<0><<<ga, TPB, 0, stream>>>(offs, csr, hb, as2, ad2, b0, nullptr, nullptr, g0b, N);

    // ---- GAT layer 1: h1 = g0@W1 -> hb (bf16), fused alpha ----
    k_mm<<<gM, TPB, 0, stream>>>(nullptr, 0, g0b, 64, nullptr, W1, nullptr, asrc1, adst1, as2, ad2, hb, N);
    k_agg<1><<<ga, TPB, 0, stream>>>(offs, csr, hb, as2, ad2, b1, ln_g, ln_b, d_out, N);

    (void)n_in; (void)ws_size; (void)out_size;
}